// Round 14
// baseline (688.708 us; speedup 1.0000x reference)
//
#include <hip/hip_runtime.h>
#include <hip/hip_bf16.h>

using bf16_t  = __hip_bfloat16;
using bf16x8  = __attribute__((ext_vector_type(8))) __bf16;
using f32x4   = __attribute__((ext_vector_type(4))) float;
using f32x16  = __attribute__((ext_vector_type(16))) float;
using u32x2   = __attribute__((ext_vector_type(2))) unsigned;

#define MFMA32(a, b, c) __builtin_amdgcn_mfma_f32_32x32x16_bf16((a), (b), (c), 0, 0, 0)

#define GLOAD_LDS(g, l) __builtin_amdgcn_global_load_lds(                      \
    (const __attribute__((address_space(1))) void*)(g),                        \
    (__attribute__((address_space(3))) void*)(l), 16, 0, 0)

static __device__ __forceinline__ unsigned pk_bf16(float lo, float hi) {
  unsigned r;
  asm volatile("v_cvt_pk_bf16_f32 %0, %1, %2" : "=v"(r) : "v"(lo), "v"(hi));
  return r;
}

static __device__ __forceinline__ void lane32_swap(unsigned& a, unsigned& b) {
#if __has_builtin(__builtin_amdgcn_permlane32_swap)
  u32x2 r = __builtin_amdgcn_permlane32_swap(a, b, false, false);
  a = r[0]; b = r[1];
#else
  asm volatile("v_permlane32_swap_b32 %0, %1" : "+v"(a), "+v"(b));
#endif
}

// B=8, C=256, N=4096(=64x64), 16 groups of 16 channels. f32 I/O, bf16 internal.

// -------- prep: GroupNorm (256 blocks) + weight cvt (64 blocks) -----------
__global__ __launch_bounds__(256) void prep_kernel(
    const float* __restrict__ xy,
    const float* __restrict__ nw,
    const float* __restrict__ nb,
    const float* __restrict__ q_w, const float* __restrict__ k_w,
    const float* __restrict__ v_w, const float* __restrict__ p_w,
    bf16_t* __restrict__ hn_t,
    bf16_t* __restrict__ yn_t,
    bf16_t* __restrict__ wdst)
{
  const int bx  = blockIdx.x;
  const int tid = threadIdx.x;

  if (bx >= 256) {                 // ---- weight conversion path ----
    const int bx2 = bx - 256;      // 64 blocks x 256 thr x 4 elems = 65536/w
    const int i = (bx2 * 256 + tid) * 4;
    const float* srcs[4] = { q_w, k_w, v_w, p_w };
    #pragma unroll
    for (int wsel = 0; wsel < 4; ++wsel) {
      float4 v = *(const float4*)(srcs[wsel] + i);
      bf16_t* d = wdst + wsel * 65536 + i;
      d[0] = __float2bfloat16(v.x);
      d[1] = __float2bfloat16(v.y);
      d[2] = __float2bfloat16(v.z);
      d[3] = __float2bfloat16(v.w);
    }
    return;
  }

  const int b     = bx >> 5;
  const int rest  = bx & 31;
  const int which = rest >> 4;
  const int g     = rest & 15;

  const float* src = xy + (((long)b * 512 + which * 256 + g * 16) << 12);
  bf16_t* dst = (which ? yn_t : hn_t) + ((long)b << 20) + g * 16;

  float sum = 0.f, ss = 0.f;
  const float4* src4 = (const float4*)src;
  for (int i = tid; i < 16384; i += 256) {
    float4 v = src4[i];
    sum += (v.x + v.y) + (v.z + v.w);
    ss = fmaf(v.x, v.x, ss); ss = fmaf(v.y, v.y, ss);
    ss = fmaf(v.z, v.z, ss); ss = fmaf(v.w, v.w, ss);
  }
  #pragma unroll
  for (int off = 32; off > 0; off >>= 1) {
    sum += __shfl_down(sum, off);
    ss  += __shfl_down(ss, off);
  }
  __shared__ float rbuf[8];
  const int w = tid >> 6, lane = tid & 63;
  if (lane == 0) { rbuf[w] = sum; rbuf[4 + w] = ss; }
  __syncthreads();
  const float inv = 1.f / 65536.f;
  const float mu  = (rbuf[0] + rbuf[1] + rbuf[2] + rbuf[3]) * inv;
  const float var = (rbuf[4] + rbuf[5] + rbuf[6] + rbuf[7]) * inv - mu * mu;
  const float rs  = rsqrtf(var + 1e-6f);

  const int   cl = tid & 15;
  const float a  = nw[g * 16 + cl] * rs;
  const float c  = nb[g * 16 + cl] - mu * a;
  const float* srow = src + ((long)cl << 12);
  for (int n = tid >> 4; n < 4096; n += 16) {
    dst[((long)n << 8) + cl] = __float2bfloat16(fmaf(srow[n], a, c));
  }
}

// -------- unified staged QKV GEMM (single-phase contiguous staging) -------
__global__ __launch_bounds__(256, 2) void gemm_qkv_kernel(
    const bf16_t* __restrict__ yn, const bf16_t* __restrict__ hn,
    const bf16_t* __restrict__ wqkv,
    bf16_t* __restrict__ q_t, bf16_t* __restrict__ k_t,
    bf16_t* __restrict__ vbuf,
    const float* __restrict__ qb, const float* __restrict__ kb,
    const float* __restrict__ vb)
{
  __shared__ bf16_t a_lds[64 * 256];
  __shared__ bf16_t b_lds[64 * 256];

  const int z     = blockIdx.z;
  const int which = z >> 3, b = z & 7;
  const long nc   = (long)4096 * 256;

  const bf16_t* Ag;
  const bf16_t* Bg;
  bf16_t* outp;
  const float* bias;
  long m0, n0;
  int Nn, brow;
  if (which == 0) {
    m0 = blockIdx.x * 64; n0 = blockIdx.y * 64;
    Ag = yn + b * nc + m0 * 256; Bg = wqkv + n0 * 256;
    outp = q_t + b * nc; bias = qb; Nn = 256; brow = 0;
  } else if (which == 1) {
    m0 = blockIdx.x * 64; n0 = blockIdx.y * 64;
    Ag = hn + b * nc + m0 * 256; Bg = wqkv + 65536 + n0 * 256;
    outp = k_t + b * nc; bias = kb; Nn = 256; brow = 0;
  } else {
    m0 = blockIdx.y * 64; n0 = blockIdx.x * 64;
    Ag = wqkv + 131072 + m0 * 256; Bg = hn + b * nc + n0 * 256;
    outp = vbuf + b * nc; bias = vb; Nn = 4096; brow = 1;
  }

  const int tid = threadIdx.x;
  const int w   = tid >> 6, lane = tid & 63;
  const int ql  = lane & 31, hi = lane >> 5;

  #pragma unroll
  for (int it = 0; it < 8; ++it) {
    const int cl  = it * 256 + tid;          // 2048 chunks of 16B
    const int r   = cl >> 5, j = cl & 31;    // 64 rows x 32 chunks
    const int off = r * 256 + ((j ^ (r & 7)) << 3);
    GLOAD_LDS(Ag + off, &a_lds[cl * 8]);
    GLOAD_LDS(Bg + off, &b_lds[cl * 8]);
  }
  __syncthreads();

  const int mb = (w & 1) * 32, nb = (w >> 1) * 32;
  const int sw = ql & 7;

  f32x16 acc = {};
  #pragma unroll
  for (int t = 0; t < 16; ++t) {
    const int ch = t * 2 + hi;
    bf16x8 af = *(const bf16x8*)(&a_lds[(mb + ql) * 256 + ((ch ^ sw) << 3)]);
    bf16x8 bf = *(const bf16x8*)(&b_lds[(nb + ql) * 256 + ((ch ^ sw) << 3)]);
    acc = MFMA32(af, bf, acc);
  }

  #pragma unroll
  for (int r = 0; r < 16; ++r) {
    const int grow = (int)m0 + mb + (r & 3) + 8 * (r >> 2) + 4 * hi;
    const int gcol = (int)n0 + nb + ql;
    float vv = acc[r] + bias[brow ? grow : gcol];
    outp[(long)grow * Nn + gcol] = __float2bfloat16(vv);
  }
}

// -------- proj GEMM with FUSED partial-merge ------------------------------
__global__ __launch_bounds__(256, 2) void gemm_proj_kernel(
    const bf16_t* __restrict__ wp,
    const bf16_t* __restrict__ P0, const bf16_t* __restrict__ P1,
    const float* __restrict__ ML,
    float* __restrict__ outp, const float* __restrict__ pb,
    const float* __restrict__ xy)
{
  __shared__ bf16_t a_lds[64 * 256];
  __shared__ bf16_t b_lds[64 * 256];

  const int b   = blockIdx.z;
  const long nc = (long)4096 * 256;
  const long m0 = blockIdx.y * 64;            // channel tile (4)
  const long n0 = blockIdx.x * 64;            // spatial tile (64)
  const bf16_t* Ag  = wp + m0 * 256;
  const bf16_t* p0r = P0 + b * nc + n0 * 256;
  const bf16_t* p1r = P1 + b * nc + n0 * 256;

  const int tid = threadIdx.x;
  const int w   = tid >> 6, lane = tid & 63;
  const int ql  = lane & 31, hi = lane >> 5;

  #pragma unroll
  for (int it = 0; it < 8; ++it) {
    const int cl  = it * 256 + tid;
    const int r   = cl >> 5, j = cl & 31;
    const int off = r * 256 + ((j ^ (r & 7)) << 3);
    GLOAD_LDS(Ag + off, &a_lds[cl * 8]);
  }

  #pragma unroll
  for (int it = 0; it < 8; ++it) {
    const int cl  = it * 256 + tid;
    const int r   = cl >> 5, j = cl & 31;
    const int off = r * 256 + ((j ^ (r & 7)) << 3);
    const long qrow = (long)b * 4096 + n0 + r;
    const float2 ml0 = *(const float2*)(ML + qrow * 2);
    const float2 ml1 = *(const float2*)(ML + (32768 + qrow) * 2);
    const float mm = fmaxf(ml0.x, ml1.x);
    const float w0 = exp2f(ml0.x - mm), w1 = exp2f(ml1.x - mm);
    const float il = 1.f / (ml0.y * w0 + ml1.y * w1);
    const float a0 = w0 * il, a1 = w1 * il;

    uint4 u0 = *(const uint4*)(p0r + off);
    uint4 u1 = *(const uint4*)(p1r + off);
    const unsigned* c0 = (const unsigned*)&u0;
    const unsigned* c1 = (const unsigned*)&u1;
    unsigned ov[4];
    #pragma unroll
    for (int k = 0; k < 4; ++k) {
      float lo0 = __uint_as_float(c0[k] << 16);
      float hi0 = __uint_as_float(c0[k] & 0xffff0000u);
      float lo1 = __uint_as_float(c1[k] << 16);
      float hi1 = __uint_as_float(c1[k] & 0xffff0000u);
      ov[k] = pk_bf16(fmaf(lo0, a0, lo1 * a1), fmaf(hi0, a0, hi1 * a1));
    }
    *(uint4*)(&b_lds[cl * 8]) = *(uint4*)ov;
  }
  __syncthreads();

  const int mb = (w & 1) * 32, nb = (w >> 1) * 32;
  const int sw = ql & 7;

  f32x16 acc = {};
  #pragma unroll
  for (int t = 0; t < 16; ++t) {
    const int ch = t * 2 + hi;
    bf16x8 af = *(const bf16x8*)(&a_lds[(mb + ql) * 256 + ((ch ^ sw) << 3)]);
    bf16x8 bf = *(const bf16x8*)(&b_lds[(nb + ql) * 256 + ((ch ^ sw) << 3)]);
    acc = MFMA32(af, bf, acc);
  }

  const float* resid = xy + (long)b * 512 * 4096;
  #pragma unroll
  for (int r = 0; r < 16; ++r) {
    const int grow = (int)m0 + mb + (r & 3) + 8 * (r >> 2) + 4 * hi;
    const int gcol = (int)n0 + nb + ql;
    float vv = acc[r] + pb[grow] + resid[(long)grow * 4096 + gcol];
    outp[(long)b * nc + (long)grow * 4096 + gcol] = vv;
  }
}

// ---------------- Flash attention (kv-split partials) ----------------------
// grid (64 q-tiles, 8 batches, 2 kv-splits) = 1024 blocks; 128 thr = 2 waves
// x 32 q-rows. KVBLK=32; LDS = K dbuf 32KB ONLY -> 4 independent blocks/CU
// (decorrelated barrier groups). V read from global (L2-resident 16KB tiles,
// ks=0 half prefetched into regs under softmax) -> zero V bank conflicts.
__global__ __launch_bounds__(128, 2) void attn_kernel(
    const bf16_t* __restrict__ Q,   // (B, N, C)
    const bf16_t* __restrict__ Kt,  // (B, N, C)
    const bf16_t* __restrict__ V,   // (B, C, N)
    bf16_t* __restrict__ P0,        // (B, N, C) partial split 0
    bf16_t* __restrict__ P1,        // (B, N, C) partial split 1
    float* __restrict__ ML)         // [split][b*4096+q] x {m, l}
{
  __shared__ bf16_t k_lds[2][32 * 256];   // 16KB/buf; row=kv, 32 chunks of 16B

  const int b     = blockIdx.y;
  const int split = blockIdx.z;
  const long bo   = (long)b << 20;
  const bf16_t* q_t = Q  + bo;
  const bf16_t* k_t = Kt + bo + (long)split * 2048 * 256;
  const bf16_t* vb  = V  + bo + split * 2048;
  bf16_t*       po  = (split ? P1 : P0) + bo;

  const int tid = threadIdx.x;
  const int w   = tid >> 6, lane = tid & 63;
  const int ql  = lane & 31, hi = lane >> 5;
  const int q0  = blockIdx.x * 64 + w * 32;

  // K staging offsets (swizzle-inverse on global source; LDS dest linear):
  // 1024 chunks of 16B over 128 threads = 8 each, lane-contiguous dests.
  int kgoff[8];
  #pragma unroll
  for (int it = 0; it < 8; ++it) {
    const int cl = it * 128 + tid;
    const int r  = cl >> 5, j = cl & 31;    // 32 rows x 32 chunks
    kgoff[it] = r * 256 + ((j ^ (r & 7)) << 3);
  }

  // Q fragments (B-operand): lane holds Q[q0+ql][cs*16 + hi*8 .. +8]
  bf16x8 qf[16];
  #pragma unroll
  for (int cs = 0; cs < 16; ++cs)
    qf[cs] = *(const bf16x8*)(q_t + (long)(q0 + ql) * 256 + cs * 16 + hi * 8);

  f32x16 o[8] = {};            // O^T[c = cb*32 + (reg&3)+8*(reg>>2)+4*hi][q=ql]
  float m2 = -1e30f, lsum = 0.f;
  const float SC2 = 0.0625f * 1.44269504f;   // scale * log2(e)

  // prologue: stage K tile 0 into buf 0
  #pragma unroll
  for (int it = 0; it < 8; ++it)
    GLOAD_LDS(k_t + kgoff[it], &k_lds[0][(it * 128 + tid) * 8]);

  int cur = 0;
  for (int t = 0; t < 64; ++t) {
    const int kv0 = t << 5;
    __syncthreads();                        // buf[cur] staged; prior reads done
    if (t < 63) {
      #pragma unroll
      for (int it = 0; it < 8; ++it)
        GLOAD_LDS(k_t + (long)(kv0 + 32) * 256 + kgoff[it],
                  &k_lds[cur ^ 1][(it * 128 + tid) * 8]);
    }

    // S^T = K . Q^T : one 32x32 tile, K from LDS (XOR-swizzled rows)
    f32x16 s0 = {};
    #pragma unroll
    for (int cs = 0; cs < 16; ++cs) {
      const int ch = cs * 2 + hi;
      bf16x8 kf = *(const bf16x8*)(
          &k_lds[cur][ql * 256 + ((ch ^ (ql & 7)) << 3)]);
      s0 = MFMA32(kf, qf[cs], s0);
    }

    // prefetch V first kv-half from global (L2-resident; hides under softmax)
    bf16x8 vf0[8];
    #pragma unroll
    for (int cb = 0; cb < 8; ++cb)
      vf0[cb] = *(const bf16x8*)(vb + (long)(cb * 32 + ql) * 4096 + kv0 + hi * 8);

    // online softmax (log2 domain); lane owns q=ql, 16 kv rows lane-local
    float p0[16];
    #pragma unroll
    for (int i = 0; i < 16; ++i) p0[i] = s0[i] * SC2;
    float mx = p0[0];
    #pragma unroll
    for (int i = 1; i < 16; ++i) mx = fmaxf(mx, p0[i]);
    mx = fmaxf(mx, __shfl_xor(mx, 32));
    if (__any(mx > m2 + 11.5f)) {           // defer-max rescale
      const float mn = fmaxf(m2, mx);
      const float al = exp2f(m2 - mn);
      m2 = mn;
      lsum *= al;
      #pragma unroll
      for (int cb = 0; cb < 8; ++cb)
        #pragma unroll
        for (int i = 0; i < 16; ++i) o[cb][i] *= al;
    }
    float sm = 0.f;
    #pragma unroll
    for (int i = 0; i < 16; ++i) {
      p0[i] = exp2f(p0[i] - m2); sm += p0[i];
    }
    sm += __shfl_xor(sm, 32);
    lsum += sm;

    // P^T B-operand assembly: cvt_pk pairs + permlane32_swap (no LDS)
    bf16x8 pb[2];
    {
      unsigned wd[8];
      #pragma unroll
      for (int j = 0; j < 8; ++j) wd[j] = pk_bf16(p0[2 * j], p0[2 * j + 1]);
      lane32_swap(wd[0], wd[2]); lane32_swap(wd[1], wd[3]);
      lane32_swap(wd[4], wd[6]); lane32_swap(wd[5], wd[7]);
      union { unsigned u[4]; bf16x8 v; } a0, a1;
      a0.u[0] = wd[0]; a0.u[1] = wd[1]; a0.u[2] = wd[2]; a0.u[3] = wd[3];
      a1.u[0] = wd[4]; a1.u[1] = wd[5]; a1.u[2] = wd[6]; a1.u[3] = wd[7];
      pb[0] = a0.v; pb[1] = a1.v;
    }

    // O^T += V . P^T ; ks=0 from prefetched regs, ks=1 loaded inline
    #pragma unroll
    for (int cb = 0; cb < 8; ++cb)
      o[cb] = MFMA32(vf0[cb], pb[0], o[cb]);
    #pragma unroll
    for (int cb = 0; cb < 8; ++cb) {
      bf16x8 vf = *(const bf16x8*)(
          vb + (long)(cb * 32 + ql) * 4096 + kv0 + 16 + hi * 8);
      o[cb] = MFMA32(vf, pb[1], o[cb]);
    }
    cur ^= 1;
  }

  // epilogue: store UNNORMALIZED O^T + (m, l)
  lsum += __shfl_xor(lsum, 32);
  lsum *= 0.5f;                             // both hi halves summed it twice
  if (hi == 0) {
    float2 ml = make_float2(m2, lsum);
    *(float2*)(ML + ((long)split * 32768 + b * 4096 + q0 + ql) * 2) = ml;
  }
  bf16_t* hrow = po + (long)(q0 + ql) * 256;
  #pragma unroll
  for (int cb = 0; cb < 8; ++cb) {
    #pragma unroll
    for (int pg = 0; pg < 4; ++pg) {
      unsigned u0 = pk_bf16(o[cb][pg * 4 + 0], o[cb][pg * 4 + 1]);
      unsigned u1 = pk_bf16(o[cb][pg * 4 + 2], o[cb][pg * 4 + 3]);
      uint2 uu = make_uint2(u0, u1);
      *(uint2*)(hrow + cb * 32 + pg * 8 + hi * 4) = uu;
    }
  }
}

extern "C" void kernel_launch(void* const* d_in, const int* in_sizes, int n_in,
                              void* d_out, int out_size, void* d_ws, size_t ws_size,
                              hipStream_t stream)
{
  const float* xy  = (const float*)d_in[0];
  const float* nw  = (const float*)d_in[1];
  const float* nb  = (const float*)d_in[2];
  const float* q_w = (const float*)d_in[3];
  const float* q_b = (const float*)d_in[4];
  const float* k_w = (const float*)d_in[5];
  const float* k_b = (const float*)d_in[6];
  const float* v_w = (const float*)d_in[7];
  const float* v_b = (const float*)d_in[8];
  const float* p_w = (const float*)d_in[9];
  const float* p_b = (const float*)d_in[10];
  float*  out = (float*)d_out;
  bf16_t* ws  = (bf16_t*)d_ws;

  const long SZ = (long)8 * 4096 * 256;
  bf16_t* wqkv = ws;                        // wq,wk,wv,wp contiguous
  bf16_t* wp   = ws + 196608;
  bf16_t* hn_t = ws + 262144;
  bf16_t* yn_t = hn_t + SZ;
  bf16_t* q_t  = hn_t + 2 * SZ;
  bf16_t* k_t  = hn_t + 3 * SZ;
  bf16_t* vbuf = hn_t + 4 * SZ;
  float*  mlb  = (float*)(hn_t + 5 * SZ);   // 2 x 32768 x float2 = 512KB
  bf16_t* part0 = hn_t;                     // dead after v GEMM
  bf16_t* part1 = yn_t;                     // dead after q GEMM

  prep_kernel<<<320, 256, 0, stream>>>(xy, nw, nb, q_w, k_w, v_w, p_w,
                                       hn_t, yn_t, wqkv);

  gemm_qkv_kernel<<<dim3(64, 4, 24), 256, 0, stream>>>(
      yn_t, hn_t, wqkv, q_t, k_t, vbuf, q_b, k_b, v_b);

  attn_kernel<<<dim3(64, 8, 2), 128, 0, stream>>>(q_t, k_t, vbuf,
                                                  part0, part1, mlb);

  gemm_proj_kernel<<<dim3(64, 4, 8), 256, 0, stream>>>(
      wp, part0, part1, mlb, out, p_b, xy);
}

// Round 15
// 358.193 us; speedup vs baseline: 1.9227x; 1.9227x over previous
//
#include <hip/hip_runtime.h>
#include <hip/hip_bf16.h>

using bf16_t  = __hip_bfloat16;
using bf16x8  = __attribute__((ext_vector_type(8))) __bf16;
using f32x4   = __attribute__((ext_vector_type(4))) float;
using f32x16  = __attribute__((ext_vector_type(16))) float;
using u32x2   = __attribute__((ext_vector_type(2))) unsigned;

#define MFMA32(a, b, c) __builtin_amdgcn_mfma_f32_32x32x16_bf16((a), (b), (c), 0, 0, 0)

#define GLOAD_LDS(g, l) __builtin_amdgcn_global_load_lds(                      \
    (const __attribute__((address_space(1))) void*)(g),                        \
    (__attribute__((address_space(3))) void*)(l), 16, 0, 0)

static __device__ __forceinline__ unsigned pk_bf16(float lo, float hi) {
  unsigned r;
  asm volatile("v_cvt_pk_bf16_f32 %0, %1, %2" : "=v"(r) : "v"(lo), "v"(hi));
  return r;
}

static __device__ __forceinline__ void lane32_swap(unsigned& a, unsigned& b) {
#if __has_builtin(__builtin_amdgcn_permlane32_swap)
  u32x2 r = __builtin_amdgcn_permlane32_swap(a, b, false, false);
  a = r[0]; b = r[1];
#else
  asm volatile("v_permlane32_swap_b32 %0, %1" : "+v"(a), "+v"(b));
#endif
}

// pairwise reduce across lane^32 WITHOUT LDS crossbar (shfl_xor(.,32) compiles
// to ds_bpermute = 32-way crossbar serialization; this is 2 VALU ops).
static __device__ __forceinline__ float pair_max32(float x) {
  unsigned a = __float_as_uint(x), b = a;
  lane32_swap(a, b);
  return fmaxf(__uint_as_float(a), __uint_as_float(b));
}
static __device__ __forceinline__ float pair_add32(float x) {
  unsigned a = __float_as_uint(x), b = a;
  lane32_swap(a, b);
  return __uint_as_float(a) + __uint_as_float(b);
}

// B=8, C=256, N=4096(=64x64), 16 groups of 16 channels. f32 I/O, bf16 internal.

// -------- prep: GroupNorm (256 blocks) + weight cvt (64 blocks) -----------
__global__ __launch_bounds__(256) void prep_kernel(
    const float* __restrict__ xy,
    const float* __restrict__ nw,
    const float* __restrict__ nb,
    const float* __restrict__ q_w, const float* __restrict__ k_w,
    const float* __restrict__ v_w, const float* __restrict__ p_w,
    bf16_t* __restrict__ hn_t,
    bf16_t* __restrict__ yn_t,
    bf16_t* __restrict__ wdst)
{
  const int bx  = blockIdx.x;
  const int tid = threadIdx.x;

  if (bx >= 256) {                 // ---- weight conversion path ----
    const int bx2 = bx - 256;      // 64 blocks x 256 thr x 4 elems = 65536/w
    const int i = (bx2 * 256 + tid) * 4;
    const float* srcs[4] = { q_w, k_w, v_w, p_w };
    #pragma unroll
    for (int wsel = 0; wsel < 4; ++wsel) {
      float4 v = *(const float4*)(srcs[wsel] + i);
      bf16_t* d = wdst + wsel * 65536 + i;
      d[0] = __float2bfloat16(v.x);
      d[1] = __float2bfloat16(v.y);
      d[2] = __float2bfloat16(v.z);
      d[3] = __float2bfloat16(v.w);
    }
    return;
  }

  const int b     = bx >> 5;
  const int rest  = bx & 31;
  const int which = rest >> 4;
  const int g     = rest & 15;

  const float* src = xy + (((long)b * 512 + which * 256 + g * 16) << 12);
  bf16_t* dst = (which ? yn_t : hn_t) + ((long)b << 20) + g * 16;

  float sum = 0.f, ss = 0.f;
  const float4* src4 = (const float4*)src;
  for (int i = tid; i < 16384; i += 256) {
    float4 v = src4[i];
    sum += (v.x + v.y) + (v.z + v.w);
    ss = fmaf(v.x, v.x, ss); ss = fmaf(v.y, v.y, ss);
    ss = fmaf(v.z, v.z, ss); ss = fmaf(v.w, v.w, ss);
  }
  #pragma unroll
  for (int off = 32; off > 0; off >>= 1) {
    sum += __shfl_down(sum, off);
    ss  += __shfl_down(ss, off);
  }
  __shared__ float rbuf[8];
  const int w = tid >> 6, lane = tid & 63;
  if (lane == 0) { rbuf[w] = sum; rbuf[4 + w] = ss; }
  __syncthreads();
  const float inv = 1.f / 65536.f;
  const float mu  = (rbuf[0] + rbuf[1] + rbuf[2] + rbuf[3]) * inv;
  const float var = (rbuf[4] + rbuf[5] + rbuf[6] + rbuf[7]) * inv - mu * mu;
  const float rs  = rsqrtf(var + 1e-6f);

  const int   cl = tid & 15;
  const float a  = nw[g * 16 + cl] * rs;
  const float c  = nb[g * 16 + cl] - mu * a;
  const float* srow = src + ((long)cl << 12);
  for (int n = tid >> 4; n < 4096; n += 16) {
    dst[((long)n << 8) + cl] = __float2bfloat16(fmaf(srow[n], a, c));
  }
}

// -------- unified staged QKV GEMM (single-phase contiguous staging) -------
__global__ __launch_bounds__(256, 2) void gemm_qkv_kernel(
    const bf16_t* __restrict__ yn, const bf16_t* __restrict__ hn,
    const bf16_t* __restrict__ wqkv,
    bf16_t* __restrict__ q_t, bf16_t* __restrict__ k_t,
    bf16_t* __restrict__ vbuf,
    const float* __restrict__ qb, const float* __restrict__ kb,
    const float* __restrict__ vb)
{
  __shared__ bf16_t a_lds[64 * 256];
  __shared__ bf16_t b_lds[64 * 256];

  const int z     = blockIdx.z;
  const int which = z >> 3, b = z & 7;
  const long nc   = (long)4096 * 256;

  const bf16_t* Ag;
  const bf16_t* Bg;
  bf16_t* outp;
  const float* bias;
  long m0, n0;
  int Nn, brow;
  if (which == 0) {
    m0 = blockIdx.x * 64; n0 = blockIdx.y * 64;
    Ag = yn + b * nc + m0 * 256; Bg = wqkv + n0 * 256;
    outp = q_t + b * nc; bias = qb; Nn = 256; brow = 0;
  } else if (which == 1) {
    m0 = blockIdx.x * 64; n0 = blockIdx.y * 64;
    Ag = hn + b * nc + m0 * 256; Bg = wqkv + 65536 + n0 * 256;
    outp = k_t + b * nc; bias = kb; Nn = 256; brow = 0;
  } else {
    m0 = blockIdx.y * 64; n0 = blockIdx.x * 64;
    Ag = wqkv + 131072 + m0 * 256; Bg = hn + b * nc + n0 * 256;
    outp = vbuf + b * nc; bias = vb; Nn = 4096; brow = 1;
  }

  const int tid = threadIdx.x;
  const int w   = tid >> 6, lane = tid & 63;
  const int ql  = lane & 31, hi = lane >> 5;

  #pragma unroll
  for (int it = 0; it < 8; ++it) {
    const int cl  = it * 256 + tid;          // 2048 chunks of 16B
    const int r   = cl >> 5, j = cl & 31;    // 64 rows x 32 chunks
    const int off = r * 256 + ((j ^ (r & 7)) << 3);
    GLOAD_LDS(Ag + off, &a_lds[cl * 8]);
    GLOAD_LDS(Bg + off, &b_lds[cl * 8]);
  }
  __syncthreads();

  const int mb = (w & 1) * 32, nb = (w >> 1) * 32;
  const int sw = ql & 7;

  f32x16 acc = {};
  #pragma unroll
  for (int t = 0; t < 16; ++t) {
    const int ch = t * 2 + hi;
    bf16x8 af = *(const bf16x8*)(&a_lds[(mb + ql) * 256 + ((ch ^ sw) << 3)]);
    bf16x8 bf = *(const bf16x8*)(&b_lds[(nb + ql) * 256 + ((ch ^ sw) << 3)]);
    acc = MFMA32(af, bf, acc);
  }

  #pragma unroll
  for (int r = 0; r < 16; ++r) {
    const int grow = (int)m0 + mb + (r & 3) + 8 * (r >> 2) + 4 * hi;
    const int gcol = (int)n0 + nb + ql;
    float vv = acc[r] + bias[brow ? grow : gcol];
    outp[(long)grow * Nn + gcol] = __float2bfloat16(vv);
  }
}

// -------- proj GEMM with FUSED partial-merge ------------------------------
__global__ __launch_bounds__(256, 2) void gemm_proj_kernel(
    const bf16_t* __restrict__ wp,
    const bf16_t* __restrict__ P0, const bf16_t* __restrict__ P1,
    const float* __restrict__ ML,
    float* __restrict__ outp, const float* __restrict__ pb,
    const float* __restrict__ xy)
{
  __shared__ bf16_t a_lds[64 * 256];
  __shared__ bf16_t b_lds[64 * 256];

  const int b   = blockIdx.z;
  const long nc = (long)4096 * 256;
  const long m0 = blockIdx.y * 64;            // channel tile (4)
  const long n0 = blockIdx.x * 64;            // spatial tile (64)
  const bf16_t* Ag  = wp + m0 * 256;
  const bf16_t* p0r = P0 + b * nc + n0 * 256;
  const bf16_t* p1r = P1 + b * nc + n0 * 256;

  const int tid = threadIdx.x;
  const int w   = tid >> 6, lane = tid & 63;
  const int ql  = lane & 31, hi = lane >> 5;

  #pragma unroll
  for (int it = 0; it < 8; ++it) {
    const int cl  = it * 256 + tid;
    const int r   = cl >> 5, j = cl & 31;
    const int off = r * 256 + ((j ^ (r & 7)) << 3);
    GLOAD_LDS(Ag + off, &a_lds[cl * 8]);
  }

  #pragma unroll
  for (int it = 0; it < 8; ++it) {
    const int cl  = it * 256 + tid;
    const int r   = cl >> 5, j = cl & 31;
    const int off = r * 256 + ((j ^ (r & 7)) << 3);
    const long qrow = (long)b * 4096 + n0 + r;
    const float2 ml0 = *(const float2*)(ML + qrow * 2);
    const float2 ml1 = *(const float2*)(ML + (32768 + qrow) * 2);
    const float mm = fmaxf(ml0.x, ml1.x);
    const float w0 = exp2f(ml0.x - mm), w1 = exp2f(ml1.x - mm);
    const float il = 1.f / (ml0.y * w0 + ml1.y * w1);
    const float a0 = w0 * il, a1 = w1 * il;

    uint4 u0 = *(const uint4*)(p0r + off);
    uint4 u1 = *(const uint4*)(p1r + off);
    const unsigned* c0 = (const unsigned*)&u0;
    const unsigned* c1 = (const unsigned*)&u1;
    unsigned ov[4];
    #pragma unroll
    for (int k = 0; k < 4; ++k) {
      float lo0 = __uint_as_float(c0[k] << 16);
      float hi0 = __uint_as_float(c0[k] & 0xffff0000u);
      float lo1 = __uint_as_float(c1[k] << 16);
      float hi1 = __uint_as_float(c1[k] & 0xffff0000u);
      ov[k] = pk_bf16(fmaf(lo0, a0, lo1 * a1), fmaf(hi0, a0, hi1 * a1));
    }
    *(uint4*)(&b_lds[cl * 8]) = *(uint4*)ov;
  }
  __syncthreads();

  const int mb = (w & 1) * 32, nb = (w >> 1) * 32;
  const int sw = ql & 7;

  f32x16 acc = {};
  #pragma unroll
  for (int t = 0; t < 16; ++t) {
    const int ch = t * 2 + hi;
    bf16x8 af = *(const bf16x8*)(&a_lds[(mb + ql) * 256 + ((ch ^ sw) << 3)]);
    bf16x8 bf = *(const bf16x8*)(&b_lds[(nb + ql) * 256 + ((ch ^ sw) << 3)]);
    acc = MFMA32(af, bf, acc);
  }

  const float* resid = xy + (long)b * 512 * 4096;
  #pragma unroll
  for (int r = 0; r < 16; ++r) {
    const int grow = (int)m0 + mb + (r & 3) + 8 * (r >> 2) + 4 * hi;
    const int gcol = (int)n0 + nb + ql;
    float vv = acc[r] + pb[grow] + resid[(long)grow * 4096 + gcol];
    outp[(long)b * nc + (long)grow * 4096 + gcol] = vv;
  }
}

// ---------------- Flash attention (kv-split partials) ----------------------
// grid (32 q-tiles, 8 batches, 2 kv-splits) = 512 blocks; 256 thr = 4 waves
// x 32 q-rows. KVBLK=32; LDS 64KB (K 2x16K XOR-swizzled + V 2x16K chunk-major)
// -> 2 INDEPENDENT blocks/CU. Softmax cross-half reduce via permlane32_swap
// (VALU) instead of shfl_xor/ds_bpermute (was 8.4M crossbar-conflict cycles).
__global__ __launch_bounds__(256, 2) void attn_kernel(
    const bf16_t* __restrict__ Q,   // (B, N, C)
    const bf16_t* __restrict__ Kt,  // (B, N, C)
    const bf16_t* __restrict__ V,   // (B, C, N)
    bf16_t* __restrict__ P0,        // (B, N, C) partial split 0
    bf16_t* __restrict__ P1,        // (B, N, C) partial split 1
    float* __restrict__ ML)         // [split][b*4096+q] x {m, l}
{
  __shared__ bf16_t k_lds[2][32 * 256];   // 16KB/buf; row=kv, 32 chunks of 16B
  __shared__ bf16_t v_lds[2][4 * 256 * 8];// 16KB/buf; chunk-major [g][c][8]

  const int b     = blockIdx.y;
  const int split = blockIdx.z;
  const long bo   = (long)b << 20;
  const bf16_t* q_t = Q  + bo;
  const bf16_t* k_t = Kt + bo + (long)split * 2048 * 256;
  const bf16_t* vb  = V  + bo + split * 2048;
  bf16_t*       po  = (split ? P1 : P0) + bo;

  const int tid = threadIdx.x;
  const int w   = tid >> 6, lane = tid & 63;
  const int ql  = lane & 31, hi = lane >> 5;
  const int q0  = blockIdx.x * 128 + w * 32;

  // staging source offsets (global elems). K: swizzle-inverse pre-applied.
  // V: chunk cl -> (c = cl&255, g = cl>>8), src = c*4096 + g*8 (+kv0).
  int kgoff[4], vgoff[4];
  #pragma unroll
  for (int it = 0; it < 4; ++it) {
    const int cl = it * 256 + tid;          // 1024 chunks of 16B each
    const int r  = cl >> 5, j = cl & 31;    // K: 32 rows x 32 chunks
    kgoff[it] = r * 256 + ((j ^ (r & 7)) << 3);
    const int c = cl & 255, g = cl >> 8;    // V: 4 kv-chunks x 256 rows
    vgoff[it] = c * 4096 + g * 8;
  }

  // Q fragments (B-operand): lane holds Q[q0+ql][cs*16 + hi*8 .. +8]
  bf16x8 qf[16];
  #pragma unroll
  for (int cs = 0; cs < 16; ++cs)
    qf[cs] = *(const bf16x8*)(q_t + (long)(q0 + ql) * 256 + cs * 16 + hi * 8);

  f32x16 o[8] = {};            // O^T[c = cb*32 + (reg&3)+8*(reg>>2)+4*hi][q=ql]
  float m2 = -1e30f, lsum = 0.f;
  const float SC2 = 0.0625f * 1.44269504f;   // scale * log2(e)

  // prologue: stage tile 0 into buf 0
  #pragma unroll
  for (int it = 0; it < 4; ++it)
    GLOAD_LDS(k_t + kgoff[it], &k_lds[0][(it * 256 + tid) * 8]);
  #pragma unroll
  for (int it = 0; it < 4; ++it)
    GLOAD_LDS(vb + vgoff[it], &v_lds[0][(it * 256 + tid) * 8]);

  int cur = 0;
  for (int t = 0; t < 64; ++t) {
    const int kv0 = t << 5;
    __syncthreads();                        // buf[cur] staged; prior reads done
    if (t < 63) {
      #pragma unroll
      for (int it = 0; it < 4; ++it)
        GLOAD_LDS(k_t + (long)(kv0 + 32) * 256 + kgoff[it],
                  &k_lds[cur ^ 1][(it * 256 + tid) * 8]);
      #pragma unroll
      for (int it = 0; it < 4; ++it)
        GLOAD_LDS(vb + (kv0 + 32) + vgoff[it],
                  &v_lds[cur ^ 1][(it * 256 + tid) * 8]);
    }

    // S^T = K . Q^T : one 32x32 tile, K from LDS (XOR-swizzled rows)
    f32x16 s0 = {};
    __builtin_amdgcn_s_setprio(1);
    #pragma unroll
    for (int cs = 0; cs < 16; ++cs) {
      const int ch = cs * 2 + hi;
      bf16x8 kf = *(const bf16x8*)(
          &k_lds[cur][ql * 256 + ((ch ^ (ql & 7)) << 3)]);
      s0 = MFMA32(kf, qf[cs], s0);
    }
    __builtin_amdgcn_s_setprio(0);

    // online softmax (log2 domain); lane owns q=ql, 16 kv rows lane-local
    float p0[16];
    #pragma unroll
    for (int i = 0; i < 16; ++i) p0[i] = s0[i] * SC2;
    float mx = p0[0];
    #pragma unroll
    for (int i = 1; i < 16; ++i) mx = fmaxf(mx, p0[i]);
    mx = pair_max32(mx);                    // lane^32 reduce, VALU-only
    if (__any(mx > m2 + 11.5f)) {           // defer-max rescale
      const float mn = fmaxf(m2, mx);
      const float al = exp2f(m2 - mn);
      m2 = mn;
      lsum *= al;
      #pragma unroll
      for (int cb = 0; cb < 8; ++cb)
        #pragma unroll
        for (int i = 0; i < 16; ++i) o[cb][i] *= al;
    }
    float sm = 0.f;
    #pragma unroll
    for (int i = 0; i < 16; ++i) {
      p0[i] = exp2f(p0[i] - m2); sm += p0[i];
    }
    lsum += pair_add32(sm);                 // lane^32 reduce, VALU-only

    // P^T B-operand assembly: cvt_pk pairs + permlane32_swap (no LDS)
    bf16x8 pb[2];
    {
      unsigned wd[8];
      #pragma unroll
      for (int j = 0; j < 8; ++j) wd[j] = pk_bf16(p0[2 * j], p0[2 * j + 1]);
      lane32_swap(wd[0], wd[2]); lane32_swap(wd[1], wd[3]);
      lane32_swap(wd[4], wd[6]); lane32_swap(wd[5], wd[7]);
      union { unsigned u[4]; bf16x8 v; } a0, a1;
      a0.u[0] = wd[0]; a0.u[1] = wd[1]; a0.u[2] = wd[2]; a0.u[3] = wd[3];
      a1.u[0] = wd[4]; a1.u[1] = wd[5]; a1.u[2] = wd[6]; a1.u[3] = wd[7];
      pb[0] = a0.v; pb[1] = a1.v;
    }

    // O^T += V . P^T, V from LDS chunk-major [g][c]
    __builtin_amdgcn_s_setprio(1);
    #pragma unroll
    for (int ks = 0; ks < 2; ++ks) {
      const int g = ks * 2 + hi;
      #pragma unroll
      for (int cb = 0; cb < 8; ++cb) {
        const int c = cb * 32 + ql;
        bf16x8 vf = *(const bf16x8*)(&v_lds[cur][(g * 256 + c) * 8]);
        o[cb] = MFMA32(vf, pb[ks], o[cb]);
      }
    }
    __builtin_amdgcn_s_setprio(0);
    cur ^= 1;
  }

  // epilogue: store UNNORMALIZED O^T + (m, l)
  if (hi == 0) {
    float2 ml = make_float2(m2, lsum);
    *(float2*)(ML + ((long)split * 32768 + b * 4096 + q0 + ql) * 2) = ml;
  }
  bf16_t* hrow = po + (long)(q0 + ql) * 256;
  #pragma unroll
  for (int cb = 0; cb < 8; ++cb) {
    #pragma unroll
    for (int pg = 0; pg < 4; ++pg) {
      unsigned u0 = pk_bf16(o[cb][pg * 4 + 0], o[cb][pg * 4 + 1]);
      unsigned u1 = pk_bf16(o[cb][pg * 4 + 2], o[cb][pg * 4 + 3]);
      uint2 uu = make_uint2(u0, u1);
      *(uint2*)(hrow + cb * 32 + pg * 8 + hi * 4) = uu;
    }
  }
}

extern "C" void kernel_launch(void* const* d_in, const int* in_sizes, int n_in,
                              void* d_out, int out_size, void* d_ws, size_t ws_size,
                              hipStream_t stream)
{
  const float* xy  = (const float*)d_in[0];
  const float* nw  = (const float*)d_in[1];
  const float* nb  = (const float*)d_in[2];
  const float* q_w = (const float*)d_in[3];
  const float* q_b = (const float*)d_in[4];
  const float* k_w = (const float*)d_in[5];
  const float* k_b = (const float*)d_in[6];
  const float* v_w = (const float*)d_in[7];
  const float* v_b = (const float*)d_in[8];
  const float* p_w = (const float*)d_in[9];
  const float* p_b = (const float*)d_in[10];
  float*  out = (float*)d_out;
  bf16_t* ws  = (bf16_t*)d_ws;

  const long SZ = (long)8 * 4096 * 256;
  bf16_t* wqkv = ws;                        // wq,wk,wv,wp contiguous
  bf16_t* wp   = ws + 196608;
  bf16_t* hn_t = ws + 262144;
  bf16_t* yn_t = hn_t + SZ;
  bf16_t* q_t  = hn_t + 2 * SZ;
  bf16_t* k_t  = hn_t + 3 * SZ;
  bf16_t* vbuf = hn_t + 4 * SZ;
  float*  mlb  = (float*)(hn_t + 5 * SZ);   // 2 x 32768 x float2 = 512KB
  bf16_t* part0 = hn_t;                     // dead after v GEMM
  bf16_t* part1 = yn_t;                     // dead after q GEMM

  prep_kernel<<<320, 256, 0, stream>>>(xy, nw, nb, q_w, k_w, v_w, p_w,
                                       hn_t, yn_t, wqkv);

  gemm_qkv_kernel<<<dim3(64, 4, 24), 256, 0, stream>>>(
      yn_t, hn_t, wqkv, q_t, k_t, vbuf, q_b, k_b, v_b);

  attn_kernel<<<dim3(32, 8, 2), 256, 0, stream>>>(q_t, k_t, vbuf,
                                                  part0, part1, mlb);

  gemm_proj_kernel<<<dim3(64, 4, 8), 256, 0, stream>>>(
      wp, part0, part1, mlb, out, p_b, xy);
}

// Round 16
// 305.806 us; speedup vs baseline: 2.2521x; 1.1713x over previous
//
#include <hip/hip_runtime.h>
#include <hip/hip_bf16.h>

using bf16_t  = __hip_bfloat16;
using bf16x8  = __attribute__((ext_vector_type(8))) __bf16;
using f32x4   = __attribute__((ext_vector_type(4))) float;
using f32x16  = __attribute__((ext_vector_type(16))) float;
using u32x2   = __attribute__((ext_vector_type(2))) unsigned;

#define MFMA32(a, b, c) __builtin_amdgcn_mfma_f32_32x32x16_bf16((a), (b), (c), 0, 0, 0)

#define GLOAD_LDS(g, l) __builtin_amdgcn_global_load_lds(                      \
    (const __attribute__((address_space(1))) void*)(g),                        \
    (__attribute__((address_space(3))) void*)(l), 16, 0, 0)

static __device__ __forceinline__ unsigned pk_bf16(float lo, float hi) {
  unsigned r;
  asm volatile("v_cvt_pk_bf16_f32 %0, %1, %2" : "=v"(r) : "v"(lo), "v"(hi));
  return r;
}

static __device__ __forceinline__ void lane32_swap(unsigned& a, unsigned& b) {
#if __has_builtin(__builtin_amdgcn_permlane32_swap)
  u32x2 r = __builtin_amdgcn_permlane32_swap(a, b, false, false);
  a = r[0]; b = r[1];
#else
  asm volatile("v_permlane32_swap_b32 %0, %1" : "+v"(a), "+v"(b));
#endif
}

// B=8, C=256, N=4096(=64x64), 16 groups of 16 channels. f32 I/O, bf16 internal.

// -------- prep: GroupNorm (256 blocks) + weight cvt (64 blocks) -----------
__global__ __launch_bounds__(256) void prep_kernel(
    const float* __restrict__ xy,
    const float* __restrict__ nw,
    const float* __restrict__ nb,
    const float* __restrict__ q_w, const float* __restrict__ k_w,
    const float* __restrict__ v_w, const float* __restrict__ p_w,
    bf16_t* __restrict__ hn_t,
    bf16_t* __restrict__ yn_t,
    bf16_t* __restrict__ wdst)
{
  const int bx  = blockIdx.x;
  const int tid = threadIdx.x;

  if (bx >= 256) {                 // ---- weight conversion path ----
    const int bx2 = bx - 256;      // 64 blocks x 256 thr x 4 elems = 65536/w
    const int i = (bx2 * 256 + tid) * 4;
    const float* srcs[4] = { q_w, k_w, v_w, p_w };
    #pragma unroll
    for (int wsel = 0; wsel < 4; ++wsel) {
      float4 v = *(const float4*)(srcs[wsel] + i);
      bf16_t* d = wdst + wsel * 65536 + i;
      d[0] = __float2bfloat16(v.x);
      d[1] = __float2bfloat16(v.y);
      d[2] = __float2bfloat16(v.z);
      d[3] = __float2bfloat16(v.w);
    }
    return;
  }

  const int b     = bx >> 5;
  const int rest  = bx & 31;
  const int which = rest >> 4;
  const int g     = rest & 15;

  const float* src = xy + (((long)b * 512 + which * 256 + g * 16) << 12);
  bf16_t* dst = (which ? yn_t : hn_t) + ((long)b << 20) + g * 16;

  float sum = 0.f, ss = 0.f;
  const float4* src4 = (const float4*)src;
  for (int i = tid; i < 16384; i += 256) {
    float4 v = src4[i];
    sum += (v.x + v.y) + (v.z + v.w);
    ss = fmaf(v.x, v.x, ss); ss = fmaf(v.y, v.y, ss);
    ss = fmaf(v.z, v.z, ss); ss = fmaf(v.w, v.w, ss);
  }
  #pragma unroll
  for (int off = 32; off > 0; off >>= 1) {
    sum += __shfl_down(sum, off);
    ss  += __shfl_down(ss, off);
  }
  __shared__ float rbuf[8];
  const int w = tid >> 6, lane = tid & 63;
  if (lane == 0) { rbuf[w] = sum; rbuf[4 + w] = ss; }
  __syncthreads();
  const float inv = 1.f / 65536.f;
  const float mu  = (rbuf[0] + rbuf[1] + rbuf[2] + rbuf[3]) * inv;
  const float var = (rbuf[4] + rbuf[5] + rbuf[6] + rbuf[7]) * inv - mu * mu;
  const float rs  = rsqrtf(var + 1e-6f);

  const int   cl = tid & 15;
  const float a  = nw[g * 16 + cl] * rs;
  const float c  = nb[g * 16 + cl] - mu * a;
  const float* srow = src + ((long)cl << 12);
  for (int n = tid >> 4; n < 4096; n += 16) {
    dst[((long)n << 8) + cl] = __float2bfloat16(fmaf(srow[n], a, c));
  }
}

// -------- unified staged QKV GEMM (single-phase contiguous staging) -------
__global__ __launch_bounds__(256, 2) void gemm_qkv_kernel(
    const bf16_t* __restrict__ yn, const bf16_t* __restrict__ hn,
    const bf16_t* __restrict__ wqkv,
    bf16_t* __restrict__ q_t, bf16_t* __restrict__ k_t,
    bf16_t* __restrict__ vbuf,
    const float* __restrict__ qb, const float* __restrict__ kb,
    const float* __restrict__ vb)
{
  __shared__ bf16_t a_lds[64 * 256];
  __shared__ bf16_t b_lds[64 * 256];

  const int z     = blockIdx.z;
  const int which = z >> 3, b = z & 7;
  const long nc   = (long)4096 * 256;

  const bf16_t* Ag;
  const bf16_t* Bg;
  bf16_t* outp;
  const float* bias;
  long m0, n0;
  int Nn, brow;
  if (which == 0) {
    m0 = blockIdx.x * 64; n0 = blockIdx.y * 64;
    Ag = yn + b * nc + m0 * 256; Bg = wqkv + n0 * 256;
    outp = q_t + b * nc; bias = qb; Nn = 256; brow = 0;
  } else if (which == 1) {
    m0 = blockIdx.x * 64; n0 = blockIdx.y * 64;
    Ag = hn + b * nc + m0 * 256; Bg = wqkv + 65536 + n0 * 256;
    outp = k_t + b * nc; bias = kb; Nn = 256; brow = 0;
  } else {
    m0 = blockIdx.y * 64; n0 = blockIdx.x * 64;
    Ag = wqkv + 131072 + m0 * 256; Bg = hn + b * nc + n0 * 256;
    outp = vbuf + b * nc; bias = vb; Nn = 4096; brow = 1;
  }

  const int tid = threadIdx.x;
  const int w   = tid >> 6, lane = tid & 63;
  const int ql  = lane & 31, hi = lane >> 5;

  #pragma unroll
  for (int it = 0; it < 8; ++it) {
    const int cl  = it * 256 + tid;          // 2048 chunks of 16B
    const int r   = cl >> 5, j = cl & 31;    // 64 rows x 32 chunks
    const int off = r * 256 + ((j ^ (r & 7)) << 3);
    GLOAD_LDS(Ag + off, &a_lds[cl * 8]);
    GLOAD_LDS(Bg + off, &b_lds[cl * 8]);
  }
  __syncthreads();

  const int mb = (w & 1) * 32, nb = (w >> 1) * 32;
  const int sw = ql & 7;

  f32x16 acc = {};
  #pragma unroll
  for (int t = 0; t < 16; ++t) {
    const int ch = t * 2 + hi;
    bf16x8 af = *(const bf16x8*)(&a_lds[(mb + ql) * 256 + ((ch ^ sw) << 3)]);
    bf16x8 bf = *(const bf16x8*)(&b_lds[(nb + ql) * 256 + ((ch ^ sw) << 3)]);
    acc = MFMA32(af, bf, acc);
  }

  #pragma unroll
  for (int r = 0; r < 16; ++r) {
    const int grow = (int)m0 + mb + (r & 3) + 8 * (r >> 2) + 4 * hi;
    const int gcol = (int)n0 + nb + ql;
    float vv = acc[r] + bias[brow ? grow : gcol];
    outp[(long)grow * Nn + gcol] = __float2bfloat16(vv);
  }
}

// -------- proj GEMM with FUSED partial-merge ------------------------------
__global__ __launch_bounds__(256, 2) void gemm_proj_kernel(
    const bf16_t* __restrict__ wp,
    const bf16_t* __restrict__ P0, const bf16_t* __restrict__ P1,
    const float* __restrict__ ML,
    float* __restrict__ outp, const float* __restrict__ pb,
    const float* __restrict__ xy)
{
  __shared__ bf16_t a_lds[64 * 256];
  __shared__ bf16_t b_lds[64 * 256];

  const int b   = blockIdx.z;
  const long nc = (long)4096 * 256;
  const long m0 = blockIdx.y * 64;            // channel tile (4)
  const long n0 = blockIdx.x * 64;            // spatial tile (64)
  const bf16_t* Ag  = wp + m0 * 256;
  const bf16_t* p0r = P0 + b * nc + n0 * 256;
  const bf16_t* p1r = P1 + b * nc + n0 * 256;

  const int tid = threadIdx.x;
  const int w   = tid >> 6, lane = tid & 63;
  const int ql  = lane & 31, hi = lane >> 5;

  #pragma unroll
  for (int it = 0; it < 8; ++it) {
    const int cl  = it * 256 + tid;
    const int r   = cl >> 5, j = cl & 31;
    const int off = r * 256 + ((j ^ (r & 7)) << 3);
    GLOAD_LDS(Ag + off, &a_lds[cl * 8]);
  }

  #pragma unroll
  for (int it = 0; it < 8; ++it) {
    const int cl  = it * 256 + tid;
    const int r   = cl >> 5, j = cl & 31;
    const int off = r * 256 + ((j ^ (r & 7)) << 3);
    const long qrow = (long)b * 4096 + n0 + r;
    const float2 ml0 = *(const float2*)(ML + qrow * 2);
    const float2 ml1 = *(const float2*)(ML + (32768 + qrow) * 2);
    const float mm = fmaxf(ml0.x, ml1.x);
    const float w0 = exp2f(ml0.x - mm), w1 = exp2f(ml1.x - mm);
    const float il = 1.f / (ml0.y * w0 + ml1.y * w1);
    const float a0 = w0 * il, a1 = w1 * il;

    uint4 u0 = *(const uint4*)(p0r + off);
    uint4 u1 = *(const uint4*)(p1r + off);
    const unsigned* c0 = (const unsigned*)&u0;
    const unsigned* c1 = (const unsigned*)&u1;
    unsigned ov[4];
    #pragma unroll
    for (int k = 0; k < 4; ++k) {
      float lo0 = __uint_as_float(c0[k] << 16);
      float hi0 = __uint_as_float(c0[k] & 0xffff0000u);
      float lo1 = __uint_as_float(c1[k] << 16);
      float hi1 = __uint_as_float(c1[k] & 0xffff0000u);
      ov[k] = pk_bf16(fmaf(lo0, a0, lo1 * a1), fmaf(hi0, a0, hi1 * a1));
    }
    *(uint4*)(&b_lds[cl * 8]) = *(uint4*)ov;
  }
  __syncthreads();

  const int mb = (w & 1) * 32, nb = (w >> 1) * 32;
  const int sw = ql & 7;

  f32x16 acc = {};
  #pragma unroll
  for (int t = 0; t < 16; ++t) {
    const int ch = t * 2 + hi;
    bf16x8 af = *(const bf16x8*)(&a_lds[(mb + ql) * 256 + ((ch ^ sw) << 3)]);
    bf16x8 bf = *(const bf16x8*)(&b_lds[(nb + ql) * 256 + ((ch ^ sw) << 3)]);
    acc = MFMA32(af, bf, acc);
  }

  const float* resid = xy + (long)b * 512 * 4096;
  #pragma unroll
  for (int r = 0; r < 16; ++r) {
    const int grow = (int)m0 + mb + (r & 3) + 8 * (r >> 2) + 4 * hi;
    const int gcol = (int)n0 + nb + ql;
    float vv = acc[r] + pb[grow] + resid[(long)grow * 4096 + gcol];
    outp[(long)b * nc + (long)grow * 4096 + gcol] = vv;
  }
}

// ---------------- Flash attention (kv-split partials) ----------------------
// grid (32 q-tiles, 8 batches, 2 kv-splits) = 512 blocks; 256 thr = 4 waves
// x 32 q-rows. KVBLK=32; LDS 64KB (K 2x16K XOR-swizzled + V 2x16K chunk-major)
// -> 2 INDEPENDENT blocks/CU -> 2 waves/SIMD from different barrier groups.
__global__ __launch_bounds__(256, 2) void attn_kernel(
    const bf16_t* __restrict__ Q,   // (B, N, C)
    const bf16_t* __restrict__ Kt,  // (B, N, C)
    const bf16_t* __restrict__ V,   // (B, C, N)
    bf16_t* __restrict__ P0,        // (B, N, C) partial split 0
    bf16_t* __restrict__ P1,        // (B, N, C) partial split 1
    float* __restrict__ ML)         // [split][b*4096+q] x {m, l}
{
  __shared__ bf16_t k_lds[2][32 * 256];   // 16KB/buf; row=kv, 32 chunks of 16B
  __shared__ bf16_t v_lds[2][4 * 256 * 8];// 16KB/buf; chunk-major [g][c][8]

  const int b     = blockIdx.y;
  const int split = blockIdx.z;
  const long bo   = (long)b << 20;
  const bf16_t* q_t = Q  + bo;
  const bf16_t* k_t = Kt + bo + (long)split * 2048 * 256;
  const bf16_t* vb  = V  + bo + split * 2048;
  bf16_t*       po  = (split ? P1 : P0) + bo;

  const int tid = threadIdx.x;
  const int w   = tid >> 6, lane = tid & 63;
  const int ql  = lane & 31, hi = lane >> 5;
  const int q0  = blockIdx.x * 128 + w * 32;

  // staging source offsets (global elems). K: swizzle-inverse pre-applied.
  // V: chunk cl -> (c = cl&255, g = cl>>8), src = c*4096 + g*8 (+kv0).
  int kgoff[4], vgoff[4];
  #pragma unroll
  for (int it = 0; it < 4; ++it) {
    const int cl = it * 256 + tid;          // 1024 chunks of 16B each
    const int r  = cl >> 5, j = cl & 31;    // K: 32 rows x 32 chunks
    kgoff[it] = r * 256 + ((j ^ (r & 7)) << 3);
    const int c = cl & 255, g = cl >> 8;    // V: 4 kv-chunks x 256 rows
    vgoff[it] = c * 4096 + g * 8;
  }

  // Q fragments (B-operand): lane holds Q[q0+ql][cs*16 + hi*8 .. +8]
  bf16x8 qf[16];
  #pragma unroll
  for (int cs = 0; cs < 16; ++cs)
    qf[cs] = *(const bf16x8*)(q_t + (long)(q0 + ql) * 256 + cs * 16 + hi * 8);

  f32x16 o[8] = {};            // O^T[c = cb*32 + (reg&3)+8*(reg>>2)+4*hi][q=ql]
  float m2 = -1e30f, lsum = 0.f;
  const float SC2 = 0.0625f * 1.44269504f;   // scale * log2(e)

  // prologue: stage tile 0 into buf 0
  #pragma unroll
  for (int it = 0; it < 4; ++it)
    GLOAD_LDS(k_t + kgoff[it], &k_lds[0][(it * 256 + tid) * 8]);
  #pragma unroll
  for (int it = 0; it < 4; ++it)
    GLOAD_LDS(vb + vgoff[it], &v_lds[0][(it * 256 + tid) * 8]);

  int cur = 0;
  for (int t = 0; t < 64; ++t) {
    const int kv0 = t << 5;
    __syncthreads();                        // buf[cur] staged; prior reads done
    if (t < 63) {
      #pragma unroll
      for (int it = 0; it < 4; ++it)
        GLOAD_LDS(k_t + (long)(kv0 + 32) * 256 + kgoff[it],
                  &k_lds[cur ^ 1][(it * 256 + tid) * 8]);
      #pragma unroll
      for (int it = 0; it < 4; ++it)
        GLOAD_LDS(vb + (kv0 + 32) + vgoff[it],
                  &v_lds[cur ^ 1][(it * 256 + tid) * 8]);
    }

    // S^T = K . Q^T : one 32x32 tile, K from LDS (XOR-swizzled rows)
    f32x16 s0 = {};
    #pragma unroll
    for (int cs = 0; cs < 16; ++cs) {
      const int ch = cs * 2 + hi;
      bf16x8 kf = *(const bf16x8*)(
          &k_lds[cur][ql * 256 + ((ch ^ (ql & 7)) << 3)]);
      s0 = MFMA32(kf, qf[cs], s0);
    }

    // online softmax (log2 domain); lane owns q=ql, 16 kv rows lane-local
    float p0[16];
    #pragma unroll
    for (int i = 0; i < 16; ++i) p0[i] = s0[i] * SC2;
    float mx = p0[0];
    #pragma unroll
    for (int i = 1; i < 16; ++i) mx = fmaxf(mx, p0[i]);
    mx = fmaxf(mx, __shfl_xor(mx, 32));
    if (__any(mx > m2 + 11.5f)) {           // defer-max rescale
      const float mn = fmaxf(m2, mx);
      const float al = exp2f(m2 - mn);
      m2 = mn;
      lsum *= al;
      #pragma unroll
      for (int cb = 0; cb < 8; ++cb)
        #pragma unroll
        for (int i = 0; i < 16; ++i) o[cb][i] *= al;
    }
    float sm = 0.f;
    #pragma unroll
    for (int i = 0; i < 16; ++i) {
      p0[i] = exp2f(p0[i] - m2); sm += p0[i];
    }
    sm += __shfl_xor(sm, 32);
    lsum += sm;

    // P^T B-operand assembly: cvt_pk pairs + permlane32_swap (no LDS)
    bf16x8 pb[2];
    {
      unsigned wd[8];
      #pragma unroll
      for (int j = 0; j < 8; ++j) wd[j] = pk_bf16(p0[2 * j], p0[2 * j + 1]);
      lane32_swap(wd[0], wd[2]); lane32_swap(wd[1], wd[3]);
      lane32_swap(wd[4], wd[6]); lane32_swap(wd[5], wd[7]);
      union { unsigned u[4]; bf16x8 v; } a0, a1;
      a0.u[0] = wd[0]; a0.u[1] = wd[1]; a0.u[2] = wd[2]; a0.u[3] = wd[3];
      a1.u[0] = wd[4]; a1.u[1] = wd[5]; a1.u[2] = wd[6]; a1.u[3] = wd[7];
      pb[0] = a0.v; pb[1] = a1.v;
    }

    // O^T += V . P^T, V from LDS chunk-major [g][c]
    #pragma unroll
    for (int ks = 0; ks < 2; ++ks) {
      const int g = ks * 2 + hi;
      #pragma unroll
      for (int cb = 0; cb < 8; ++cb) {
        const int c = cb * 32 + ql;
        bf16x8 vf = *(const bf16x8*)(&v_lds[cur][(g * 256 + c) * 8]);
        o[cb] = MFMA32(vf, pb[ks], o[cb]);
      }
    }
    cur ^= 1;
  }

  // epilogue: store UNNORMALIZED O^T + (m, l)
  if (hi == 0) {
    float2 ml = make_float2(m2, lsum);
    *(float2*)(ML + ((long)split * 32768 + b * 4096 + q0 + ql) * 2) = ml;
  }
  bf16_t* hrow = po + (long)(q0 + ql) * 256;
  #pragma unroll
  for (int cb = 0; cb < 8; ++cb) {
    #pragma unroll
    for (int pg = 0; pg < 4; ++pg) {
      unsigned u0 = pk_bf16(o[cb][pg * 4 + 0], o[cb][pg * 4 + 1]);
      unsigned u1 = pk_bf16(o[cb][pg * 4 + 2], o[cb][pg * 4 + 3]);
      uint2 uu = make_uint2(u0, u1);
      *(uint2*)(hrow + cb * 32 + pg * 8 + hi * 4) = uu;
    }
  }
}

extern "C" void kernel_launch(void* const* d_in, const int* in_sizes, int n_in,
                              void* d_out, int out_size, void* d_ws, size_t ws_size,
                              hipStream_t stream)
{
  const float* xy  = (const float*)d_in[0];
  const float* nw  = (const float*)d_in[1];
  const float* nb  = (const float*)d_in[2];
  const float* q_w = (const float*)d_in[3];
  const float* q_b = (const float*)d_in[4];
  const float* k_w = (const float*)d_in[5];
  const float* k_b = (const float*)d_in[6];
  const float* v_w = (const float*)d_in[7];
  const float* v_b = (const float*)d_in[8];
  const float* p_w = (const float*)d_in[9];
  const float* p_b = (const float*)d_in[10];
  float*  out = (float*)d_out;
  bf16_t* ws  = (bf16_t*)d_ws;

  const long SZ = (long)8 * 4096 * 256;
  bf16_t* wqkv = ws;                        // wq,wk,wv,wp contiguous
  bf16_t* wp   = ws + 196608;
  bf16_t* hn_t = ws + 262144;
  bf16_t* yn_t = hn_t + SZ;
  bf16_t* q_t  = hn_t + 2 * SZ;
  bf16_t* k_t  = hn_t + 3 * SZ;
  bf16_t* vbuf = hn_t + 4 * SZ;
  float*  mlb  = (float*)(hn_t + 5 * SZ);   // 2 x 32768 x float2 = 512KB
  bf16_t* part0 = hn_t;                     // dead after v GEMM
  bf16_t* part1 = yn_t;                     // dead after q GEMM

  prep_kernel<<<320, 256, 0, stream>>>(xy, nw, nb, q_w, k_w, v_w, p_w,
                                       hn_t, yn_t, wqkv);

  gemm_qkv_kernel<<<dim3(64, 4, 24), 256, 0, stream>>>(
      yn_t, hn_t, wqkv, q_t, k_t, vbuf, q_b, k_b, v_b);

  attn_kernel<<<dim3(32, 8, 2), 256, 0, stream>>>(q_t, k_t, vbuf,
                                                  part0, part1, mlb);

  gemm_proj_kernel<<<dim3(64, 4, 8), 256, 0, stream>>>(
      wp, part0, part1, mlb, out, p_b, xy);
}

// Round 17
// 278.757 us; speedup vs baseline: 2.4706x; 1.0970x over previous
//
#include <hip/hip_runtime.h>
#include <hip/hip_bf16.h>

using bf16_t  = __hip_bfloat16;
using bf16x8  = __attribute__((ext_vector_type(8))) __bf16;
using f32x4   = __attribute__((ext_vector_type(4))) float;
using f32x16  = __attribute__((ext_vector_type(16))) float;
using u32x2   = __attribute__((ext_vector_type(2))) unsigned;

#define MFMA32(a, b, c) __builtin_amdgcn_mfma_f32_32x32x16_bf16((a), (b), (c), 0, 0, 0)

#define GLOAD_LDS(g, l) __builtin_amdgcn_global_load_lds(                      \
    (const __attribute__((address_space(1))) void*)(g),                        \
    (__attribute__((address_space(3))) void*)(l), 16, 0, 0)

#define SC2 0.09016844f   // (1/16) * log2(e): softmax scale folded into Q

static __device__ __forceinline__ unsigned pk_bf16(float lo, float hi) {
  unsigned r;
  asm volatile("v_cvt_pk_bf16_f32 %0, %1, %2" : "=v"(r) : "v"(lo), "v"(hi));
  return r;
}

static __device__ __forceinline__ void lane32_swap(unsigned& a, unsigned& b) {
#if __has_builtin(__builtin_amdgcn_permlane32_swap)
  u32x2 r = __builtin_amdgcn_permlane32_swap(a, b, false, false);
  a = r[0]; b = r[1];
#else
  asm volatile("v_permlane32_swap_b32 %0, %1" : "+v"(a), "+v"(b));
#endif
}

static __device__ __forceinline__ float max3f(float a, float b, float c) {
  return fmaxf(fmaxf(a, b), c);   // clang fuses to v_max3_f32
}

// B=8, C=256, N=4096(=64x64), 16 groups of 16 channels. f32 I/O, bf16 internal.

// -------- prep: GroupNorm (256 blocks) + weight cvt (64 blocks) -----------
__global__ __launch_bounds__(256) void prep_kernel(
    const float* __restrict__ xy,
    const float* __restrict__ nw,
    const float* __restrict__ nb,
    const float* __restrict__ q_w, const float* __restrict__ k_w,
    const float* __restrict__ v_w, const float* __restrict__ p_w,
    bf16_t* __restrict__ hn_t,
    bf16_t* __restrict__ yn_t,
    bf16_t* __restrict__ wdst)
{
  const int bx  = blockIdx.x;
  const int tid = threadIdx.x;

  if (bx >= 256) {                 // ---- weight conversion path ----
    const int bx2 = bx - 256;      // 64 blocks x 256 thr x 4 elems = 65536/w
    const int i = (bx2 * 256 + tid) * 4;
    const float* srcs[4] = { q_w, k_w, v_w, p_w };
    #pragma unroll
    for (int wsel = 0; wsel < 4; ++wsel) {
      const float s = (wsel == 0) ? SC2 : 1.f;   // fold softmax scale into wq
      float4 v = *(const float4*)(srcs[wsel] + i);
      bf16_t* d = wdst + wsel * 65536 + i;
      d[0] = __float2bfloat16(v.x * s);
      d[1] = __float2bfloat16(v.y * s);
      d[2] = __float2bfloat16(v.z * s);
      d[3] = __float2bfloat16(v.w * s);
    }
    return;
  }

  const int b     = bx >> 5;
  const int rest  = bx & 31;
  const int which = rest >> 4;
  const int g     = rest & 15;

  const float* src = xy + (((long)b * 512 + which * 256 + g * 16) << 12);
  bf16_t* dst = (which ? yn_t : hn_t) + ((long)b << 20) + g * 16;

  float sum = 0.f, ss = 0.f;
  const float4* src4 = (const float4*)src;
  for (int i = tid; i < 16384; i += 256) {
    float4 v = src4[i];
    sum += (v.x + v.y) + (v.z + v.w);
    ss = fmaf(v.x, v.x, ss); ss = fmaf(v.y, v.y, ss);
    ss = fmaf(v.z, v.z, ss); ss = fmaf(v.w, v.w, ss);
  }
  #pragma unroll
  for (int off = 32; off > 0; off >>= 1) {
    sum += __shfl_down(sum, off);
    ss  += __shfl_down(ss, off);
  }
  __shared__ float rbuf[8];
  const int w = tid >> 6, lane = tid & 63;
  if (lane == 0) { rbuf[w] = sum; rbuf[4 + w] = ss; }
  __syncthreads();
  const float inv = 1.f / 65536.f;
  const float mu  = (rbuf[0] + rbuf[1] + rbuf[2] + rbuf[3]) * inv;
  const float var = (rbuf[4] + rbuf[5] + rbuf[6] + rbuf[7]) * inv - mu * mu;
  const float rs  = rsqrtf(var + 1e-6f);

  // pass 2: float4 reads -> per wave, 4 consecutive n-slots cover 64B
  // contiguous per channel-row (full L2 line; was 16B/64B = 4x over-read).
  const int   cl = tid & 15;
  const float a  = nw[g * 16 + cl] * rs;
  const float c  = nb[g * 16 + cl] - mu * a;
  const float4* srow4 = (const float4*)(src + ((long)cl << 12));
  for (int n4 = tid >> 4; n4 < 1024; n4 += 16) {
    float4 v = srow4[n4];
    const long n = (long)n4 * 4;
    dst[((n + 0) << 8) + cl] = __float2bfloat16(fmaf(v.x, a, c));
    dst[((n + 1) << 8) + cl] = __float2bfloat16(fmaf(v.y, a, c));
    dst[((n + 2) << 8) + cl] = __float2bfloat16(fmaf(v.z, a, c));
    dst[((n + 3) << 8) + cl] = __float2bfloat16(fmaf(v.w, a, c));
  }
}

// -------- unified staged QKV GEMM (single-phase contiguous staging) -------
__global__ __launch_bounds__(256, 2) void gemm_qkv_kernel(
    const bf16_t* __restrict__ yn, const bf16_t* __restrict__ hn,
    const bf16_t* __restrict__ wqkv,
    bf16_t* __restrict__ q_t, bf16_t* __restrict__ k_t,
    bf16_t* __restrict__ vbuf,
    const float* __restrict__ qb, const float* __restrict__ kb,
    const float* __restrict__ vb)
{
  __shared__ bf16_t a_lds[64 * 256];
  __shared__ bf16_t b_lds[64 * 256];

  const int z     = blockIdx.z;
  const int which = z >> 3, b = z & 7;
  const long nc   = (long)4096 * 256;

  const bf16_t* Ag;
  const bf16_t* Bg;
  bf16_t* outp;
  const float* bias;
  long m0, n0;
  int Nn, brow;
  float bscale = 1.f;
  if (which == 0) {
    m0 = blockIdx.x * 64; n0 = blockIdx.y * 64;
    Ag = yn + b * nc + m0 * 256; Bg = wqkv + n0 * 256;
    outp = q_t + b * nc; bias = qb; Nn = 256; brow = 0;
    bscale = SC2;                    // q bias also carries the folded scale
  } else if (which == 1) {
    m0 = blockIdx.x * 64; n0 = blockIdx.y * 64;
    Ag = hn + b * nc + m0 * 256; Bg = wqkv + 65536 + n0 * 256;
    outp = k_t + b * nc; bias = kb; Nn = 256; brow = 0;
  } else {
    m0 = blockIdx.y * 64; n0 = blockIdx.x * 64;
    Ag = wqkv + 131072 + m0 * 256; Bg = hn + b * nc + n0 * 256;
    outp = vbuf + b * nc; bias = vb; Nn = 4096; brow = 1;
  }

  const int tid = threadIdx.x;
  const int w   = tid >> 6, lane = tid & 63;
  const int ql  = lane & 31, hi = lane >> 5;

  #pragma unroll
  for (int it = 0; it < 8; ++it) {
    const int cl  = it * 256 + tid;          // 2048 chunks of 16B
    const int r   = cl >> 5, j = cl & 31;    // 64 rows x 32 chunks
    const int off = r * 256 + ((j ^ (r & 7)) << 3);
    GLOAD_LDS(Ag + off, &a_lds[cl * 8]);
    GLOAD_LDS(Bg + off, &b_lds[cl * 8]);
  }
  __syncthreads();

  const int mb = (w & 1) * 32, nb = (w >> 1) * 32;
  const int sw = ql & 7;

  f32x16 acc = {};
  #pragma unroll
  for (int t = 0; t < 16; ++t) {
    const int ch = t * 2 + hi;
    bf16x8 af = *(const bf16x8*)(&a_lds[(mb + ql) * 256 + ((ch ^ sw) << 3)]);
    bf16x8 bf = *(const bf16x8*)(&b_lds[(nb + ql) * 256 + ((ch ^ sw) << 3)]);
    acc = MFMA32(af, bf, acc);
  }

  #pragma unroll
  for (int r = 0; r < 16; ++r) {
    const int grow = (int)m0 + mb + (r & 3) + 8 * (r >> 2) + 4 * hi;
    const int gcol = (int)n0 + nb + ql;
    float vv = acc[r] + bias[brow ? grow : gcol] * bscale;
    outp[(long)grow * Nn + gcol] = __float2bfloat16(vv);
  }
}

// -------- proj GEMM with FUSED partial-merge ------------------------------
__global__ __launch_bounds__(256, 2) void gemm_proj_kernel(
    const bf16_t* __restrict__ wp,
    const bf16_t* __restrict__ P0, const bf16_t* __restrict__ P1,
    const float* __restrict__ ML,
    float* __restrict__ outp, const float* __restrict__ pb,
    const float* __restrict__ xy)
{
  __shared__ bf16_t a_lds[64 * 256];
  __shared__ bf16_t b_lds[64 * 256];

  const int b   = blockIdx.z;
  const long nc = (long)4096 * 256;
  const long m0 = blockIdx.y * 64;            // channel tile (4)
  const long n0 = blockIdx.x * 64;            // spatial tile (64)
  const bf16_t* Ag  = wp + m0 * 256;
  const bf16_t* p0r = P0 + b * nc + n0 * 256;
  const bf16_t* p1r = P1 + b * nc + n0 * 256;

  const int tid = threadIdx.x;
  const int w   = tid >> 6, lane = tid & 63;
  const int ql  = lane & 31, hi = lane >> 5;

  #pragma unroll
  for (int it = 0; it < 8; ++it) {
    const int cl  = it * 256 + tid;
    const int r   = cl >> 5, j = cl & 31;
    const int off = r * 256 + ((j ^ (r & 7)) << 3);
    GLOAD_LDS(Ag + off, &a_lds[cl * 8]);
  }

  #pragma unroll
  for (int it = 0; it < 8; ++it) {
    const int cl  = it * 256 + tid;
    const int r   = cl >> 5, j = cl & 31;
    const int off = r * 256 + ((j ^ (r & 7)) << 3);
    const long qrow = (long)b * 4096 + n0 + r;
    const float2 ml0 = *(const float2*)(ML + qrow * 2);
    const float2 ml1 = *(const float2*)(ML + (32768 + qrow) * 2);
    const float mm = fmaxf(ml0.x, ml1.x);
    const float w0 = exp2f(ml0.x - mm), w1 = exp2f(ml1.x - mm);
    const float il = 1.f / (ml0.y * w0 + ml1.y * w1);
    const float a0 = w0 * il, a1 = w1 * il;

    uint4 u0 = *(const uint4*)(p0r + off);
    uint4 u1 = *(const uint4*)(p1r + off);
    const unsigned* c0 = (const unsigned*)&u0;
    const unsigned* c1 = (const unsigned*)&u1;
    unsigned ov[4];
    #pragma unroll
    for (int k = 0; k < 4; ++k) {
      float lo0 = __uint_as_float(c0[k] << 16);
      float hi0 = __uint_as_float(c0[k] & 0xffff0000u);
      float lo1 = __uint_as_float(c1[k] << 16);
      float hi1 = __uint_as_float(c1[k] & 0xffff0000u);
      ov[k] = pk_bf16(fmaf(lo0, a0, lo1 * a1), fmaf(hi0, a0, hi1 * a1));
    }
    *(uint4*)(&b_lds[cl * 8]) = *(uint4*)ov;
  }
  __syncthreads();

  const int mb = (w & 1) * 32, nb = (w >> 1) * 32;
  const int sw = ql & 7;

  f32x16 acc = {};
  #pragma unroll
  for (int t = 0; t < 16; ++t) {
    const int ch = t * 2 + hi;
    bf16x8 af = *(const bf16x8*)(&a_lds[(mb + ql) * 256 + ((ch ^ sw) << 3)]);
    bf16x8 bf = *(const bf16x8*)(&b_lds[(nb + ql) * 256 + ((ch ^ sw) << 3)]);
    acc = MFMA32(af, bf, acc);
  }

  const float* resid = xy + (long)b * 512 * 4096;
  #pragma unroll
  for (int r = 0; r < 16; ++r) {
    const int grow = (int)m0 + mb + (r & 3) + 8 * (r >> 2) + 4 * hi;
    const int gcol = (int)n0 + nb + ql;
    float vv = acc[r] + pb[grow] + resid[(long)grow * 4096 + gcol];
    outp[(long)b * nc + (long)grow * 4096 + gcol] = vv;
  }
}

// ---------------- Flash attention (kv-split partials) ----------------------
// grid (32 q-tiles, 8 batches, 2 kv-splits) = 512 blocks; 256 thr = 4 waves
// x 32 q-rows. KVBLK=32; LDS 64KB (K 2x16K XOR-swizzled + V 2x16K chunk-major)
// -> 2 INDEPENDENT blocks/CU. Softmax scale pre-folded into Q (log2 domain).
__global__ __launch_bounds__(256, 2) void attn_kernel(
    const bf16_t* __restrict__ Q,   // (B, N, C), pre-scaled by SC2
    const bf16_t* __restrict__ Kt,  // (B, N, C)
    const bf16_t* __restrict__ V,   // (B, C, N)
    bf16_t* __restrict__ P0,        // (B, N, C) partial split 0
    bf16_t* __restrict__ P1,        // (B, N, C) partial split 1
    float* __restrict__ ML)         // [split][b*4096+q] x {m, l}
{
  __shared__ bf16_t k_lds[2][32 * 256];   // 16KB/buf; row=kv, 32 chunks of 16B
  __shared__ bf16_t v_lds[2][4 * 256 * 8];// 16KB/buf; chunk-major [g][c][8]

  const int b     = blockIdx.y;
  const int split = blockIdx.z;
  const long bo   = (long)b << 20;
  const bf16_t* q_t = Q  + bo;
  const bf16_t* k_t = Kt + bo + (long)split * 2048 * 256;
  const bf16_t* vb  = V  + bo + split * 2048;
  bf16_t*       po  = (split ? P1 : P0) + bo;

  const int tid = threadIdx.x;
  const int w   = tid >> 6, lane = tid & 63;
  const int ql  = lane & 31, hi = lane >> 5;
  const int q0  = blockIdx.x * 128 + w * 32;

  // staging source offsets (global elems). K: swizzle-inverse pre-applied.
  // V: chunk cl -> (c = cl&255, g = cl>>8), src = c*4096 + g*8 (+kv0).
  int kgoff[4], vgoff[4];
  #pragma unroll
  for (int it = 0; it < 4; ++it) {
    const int cl = it * 256 + tid;          // 1024 chunks of 16B each
    const int r  = cl >> 5, j = cl & 31;    // K: 32 rows x 32 chunks
    kgoff[it] = r * 256 + ((j ^ (r & 7)) << 3);
    const int c = cl & 255, g = cl >> 8;    // V: 4 kv-chunks x 256 rows
    vgoff[it] = c * 4096 + g * 8;
  }

  // Q fragments (B-operand): lane holds Q[q0+ql][cs*16 + hi*8 .. +8]
  bf16x8 qf[16];
  #pragma unroll
  for (int cs = 0; cs < 16; ++cs)
    qf[cs] = *(const bf16x8*)(q_t + (long)(q0 + ql) * 256 + cs * 16 + hi * 8);

  f32x16 o[8] = {};            // O^T[c = cb*32 + (reg&3)+8*(reg>>2)+4*hi][q=ql]
  float m2 = -1e30f, lsum = 0.f;

  // prologue: stage tile 0 into buf 0
  #pragma unroll
  for (int it = 0; it < 4; ++it)
    GLOAD_LDS(k_t + kgoff[it], &k_lds[0][(it * 256 + tid) * 8]);
  #pragma unroll
  for (int it = 0; it < 4; ++it)
    GLOAD_LDS(vb + vgoff[it], &v_lds[0][(it * 256 + tid) * 8]);

  int cur = 0;
  for (int t = 0; t < 64; ++t) {
    const int kv0 = t << 5;
    __syncthreads();                        // buf[cur] staged; prior reads done
    if (t < 63) {
      #pragma unroll
      for (int it = 0; it < 4; ++it)
        GLOAD_LDS(k_t + (long)(kv0 + 32) * 256 + kgoff[it],
                  &k_lds[cur ^ 1][(it * 256 + tid) * 8]);
      #pragma unroll
      for (int it = 0; it < 4; ++it)
        GLOAD_LDS(vb + (kv0 + 32) + vgoff[it],
                  &v_lds[cur ^ 1][(it * 256 + tid) * 8]);
    }

    // S^T = K . Q^T : one 32x32 tile, K from LDS (XOR-swizzled rows);
    // result already scaled to log2 domain (SC2 folded into Q).
    f32x16 s0 = {};
    #pragma unroll
    for (int cs = 0; cs < 16; ++cs) {
      const int ch = cs * 2 + hi;
      bf16x8 kf = *(const bf16x8*)(
          &k_lds[cur][ql * 256 + ((ch ^ (ql & 7)) << 3)]);
      s0 = MFMA32(kf, qf[cs], s0);
    }

    // online softmax; lane owns q=ql, 16 kv rows lane-local.
    // max via max3-fusable triples (depth ~8), sum via pairwise tree.
    float p0[16];
    #pragma unroll
    for (int i = 0; i < 16; ++i) p0[i] = s0[i];
    float mx = max3f(p0[0], p0[1], p0[2]);
    mx = max3f(mx, p0[3], p0[4]);
    mx = max3f(mx, p0[5], p0[6]);
    mx = max3f(mx, p0[7], p0[8]);
    mx = max3f(mx, p0[9], p0[10]);
    mx = max3f(mx, p0[11], p0[12]);
    mx = max3f(mx, p0[13], p0[14]);
    mx = fmaxf(mx, p0[15]);
    mx = fmaxf(mx, __shfl_xor(mx, 32));
    if (__any(mx > m2 + 11.5f)) {           // defer-max rescale
      const float mn = fmaxf(m2, mx);
      const float al = exp2f(m2 - mn);
      m2 = mn;
      lsum *= al;
      #pragma unroll
      for (int cb = 0; cb < 8; ++cb)
        #pragma unroll
        for (int i = 0; i < 16; ++i) o[cb][i] *= al;
    }
    #pragma unroll
    for (int i = 0; i < 16; ++i) p0[i] = exp2f(p0[i] - m2);
    float s8[8];
    #pragma unroll
    for (int i = 0; i < 8; ++i) s8[i] = p0[i] + p0[i + 8];
    float s4a = (s8[0] + s8[1]) + (s8[2] + s8[3]);
    float s4b = (s8[4] + s8[5]) + (s8[6] + s8[7]);
    float sm = s4a + s4b;
    sm += __shfl_xor(sm, 32);
    lsum += sm;

    // P^T B-operand assembly: cvt_pk pairs + permlane32_swap (no LDS)
    bf16x8 pb[2];
    {
      unsigned wd[8];
      #pragma unroll
      for (int j = 0; j < 8; ++j) wd[j] = pk_bf16(p0[2 * j], p0[2 * j + 1]);
      lane32_swap(wd[0], wd[2]); lane32_swap(wd[1], wd[3]);
      lane32_swap(wd[4], wd[6]); lane32_swap(wd[5], wd[7]);
      union { unsigned u[4]; bf16x8 v; } a0, a1;
      a0.u[0] = wd[0]; a0.u[1] = wd[1]; a0.u[2] = wd[2]; a0.u[3] = wd[3];
      a1.u[0] = wd[4]; a1.u[1] = wd[5]; a1.u[2] = wd[6]; a1.u[3] = wd[7];
      pb[0] = a0.v; pb[1] = a1.v;
    }

    // O^T += V . P^T, V from LDS chunk-major [g][c]
    #pragma unroll
    for (int ks = 0; ks < 2; ++ks) {
      const int g = ks * 2 + hi;
      #pragma unroll
      for (int cb = 0; cb < 8; ++cb) {
        const int c = cb * 32 + ql;
        bf16x8 vf = *(const bf16x8*)(&v_lds[cur][(g * 256 + c) * 8]);
        o[cb] = MFMA32(vf, pb[ks], o[cb]);
      }
    }
    cur ^= 1;
  }

  // epilogue: store UNNORMALIZED O^T + (m, l)
  if (hi == 0) {
    float2 ml = make_float2(m2, lsum);
    *(float2*)(ML + ((long)split * 32768 + b * 4096 + q0 + ql) * 2) = ml;
  }
  bf16_t* hrow = po + (long)(q0 + ql) * 256;
  #pragma unroll
  for (int cb = 0; cb < 8; ++cb) {
    #pragma unroll
    for (int pg = 0; pg < 4; ++pg) {
      unsigned u0 = pk_bf16(o[cb][pg * 4 + 0], o[cb][pg * 4 + 1]);
      unsigned u1 = pk_bf16(o[cb][pg * 4 + 2], o[cb][pg * 4 + 3]);
      uint2 uu = make_uint2(u0, u1);
      *(uint2*)(hrow + cb * 32 + pg * 8 + hi * 4) = uu;
    }
  }
}

extern "C" void kernel_launch(void* const* d_in, const int* in_sizes, int n_in,
                              void* d_out, int out_size, void* d_ws, size_t ws_size,
                              hipStream_t stream)
{
  const float* xy  = (const float*)d_in[0];
  const float* nw  = (const float*)d_in[1];
  const float* nb  = (const float*)d_in[2];
  const float* q_w = (const float*)d_in[3];
  const float* q_b = (const float*)d_in[4];
  const float* k_w = (const float*)d_in[5];
  const float* k_b = (const float*)d_in[6];
  const float* v_w = (const float*)d_in[7];
  const float* v_b = (const float*)d_in[8];
  const float* p_w = (const float*)d_in[9];
  const float* p_b = (const float*)d_in[10];
  float*  out = (float*)d_out;
  bf16_t* ws  = (bf16_t*)d_ws;

  const long SZ = (long)8 * 4096 * 256;
  bf16_t* wqkv = ws;                        // wq,wk,wv,wp contiguous
  bf16_t* wp   = ws + 196608;
  bf16_t* hn_t = ws + 262144;
  bf16_t* yn_t = hn_t + SZ;
  bf16_t* q_t  = hn_t + 2 * SZ;
  bf16_t* k_t  = hn_t + 3 * SZ;
  bf16_t* vbuf = hn_t + 4 * SZ;
  float*  mlb  = (float*)(hn_t + 5 * SZ);   // 2 x 32768 x float2 = 512KB
  bf16_t* part0 = hn_t;                     // dead after v GEMM
  bf16_t* part1 = yn_t;                     // dead after q GEMM

  prep_kernel<<<320, 256, 0, stream>>>(xy, nw, nb, q_w, k_w, v_w, p_w,
                                       hn_t, yn_t, wqkv);

  gemm_qkv_kernel<<<dim3(64, 4, 24), 256, 0, stream>>>(
      yn_t, hn_t, wqkv, q_t, k_t, vbuf, q_b, k_b, v_b);

  attn_kernel<<<dim3(32, 8, 2), 256, 0, stream>>>(q_t, k_t, vbuf,
                                                  part0, part1, mlb);

  gemm_proj_kernel<<<dim3(64, 4, 8), 256, 0, stream>>>(
      wp, part0, part1, mlb, out, p_b, xy);
}